// Round 4
// baseline (715.654 us; speedup 1.0000x reference)
//
#include <hip/hip_runtime.h>
#include <math.h>

#define N_B 64
#define N_ICAPS 2048
#define N_IDIMS 8
#define N_NCAPS 32
#define N_DIMS 16

__device__ __forceinline__ float softplus_f(float z) {
    return (z > 15.0f) ? z : log1pf(__expf(z));
}

// K1: W = loc + (1e-5 + softplus(C + scale_raw)) * eps    (8,388,608 floats)
__global__ __launch_bounds__(256) void compute_w(const float4* __restrict__ loc,
                                                 const float4* __restrict__ sr,
                                                 const float4* __restrict__ eps,
                                                 float4* __restrict__ W) {
    const float C = 0.5413248546129181f;  // log(expm1(1))
    int idx = blockIdx.x * 256 + threadIdx.x;   // 2,097,152 float4s total
    float4 l = loc[idx], s = sr[idx], e = eps[idx];
    float4 o;
    o.x = fmaf(1e-5f + softplus_f(C + s.x), e.x, l.x);
    o.y = fmaf(1e-5f + softplus_f(C + s.y), e.y, l.y);
    o.z = fmaf(1e-5f + softplus_f(C + s.z), e.z, l.z);
    o.w = fmaf(1e-5f + softplus_f(C + s.w), e.w, l.w);
    W[idx] = o;
}

// K2: one routing pass. T = iteration index (0,1,2).
// Grid: 512 blocks = 8 b-groups x 64 i-chunks; block = 8 waves (512 thr).
// Wave w handles b in [bg*8, bg*8+8), i in [ci*32 + w*4, +4).
// Lane l: j = l>>1, d-range = (l&1)*8 .. +8.
// __launch_bounds__(512, 1): live set is Wr[64]+sacc[64]+temps ~ 160 VGPR.
// (512,2) clamped the allocator to 128 VGPR -> ~280 MB/dispatch scratch
// spill traffic, VALUBusy 7.8% (R3 profile). One wave-pair per SIMD with
// zero spills beats four with spills.
template<int T>
__global__ __launch_bounds__(512, 1) void route_pass(
        const float* __restrict__ W, const float* __restrict__ x,
        const float* __restrict__ v0, const float* __restrict__ v1,
        float* __restrict__ s_part, float* __restrict__ c_out) {
    __shared__ float s_lds[8 * 512];
    const int tid = threadIdx.x;
    const int w = tid >> 6;
    const int l = tid & 63;
    const int bg = blockIdx.x & 7;
    const int ci = blockIdx.x >> 3;
    const int b0 = bg * 8;
    const int i0 = ci * 32 + w * 4;
    const int j = l >> 1;
    const int d0 = (l & 1) * 8;

    float sacc[8][8];
    #pragma unroll
    for (int a = 0; a < 8; ++a)
        #pragma unroll
        for (int c2 = 0; c2 < 8; ++c2) sacc[a][c2] = 0.0f;

    for (int ii = 0; ii < 4; ++ii) {
        const int i = i0 + ii;
        // lane's W slice: 64 consecutive floats at W + i*4096 + l*64
        // = W[i][j = l>>1][d0 + 0..7][0..7]  (row-major i,j,d,k)
        float Wr[64];
        const float4* wp = reinterpret_cast<const float4*>(W + (size_t)i * 4096 + l * 64);
        #pragma unroll
        for (int q = 0; q < 16; ++q) {
            float4 t = wp[q];
            Wr[q * 4 + 0] = t.x; Wr[q * 4 + 1] = t.y;
            Wr[q * 4 + 2] = t.z; Wr[q * 4 + 3] = t.w;
        }
        #pragma unroll
        for (int bb = 0; bb < 8; ++bb) {
            const int b = b0 + bb;
            const float4* xp = reinterpret_cast<const float4*>(x + ((size_t)b * N_ICAPS + i) * N_IDIMS);
            float4 xa = xp[0], xb = xp[1];
            float xr[8] = {xa.x, xa.y, xa.z, xa.w, xb.x, xb.y, xb.z, xb.w};
            float u[8];
            #pragma unroll
            for (int dd = 0; dd < 8; ++dd) {
                float acc = 0.0f;
                #pragma unroll
                for (int k = 0; k < 8; ++k) acc = fmaf(Wr[dd * 8 + k], xr[k], acc);
                u[dd] = acc;
            }
            float c;
            if (T == 0) {
                c = 1.0f / 32.0f;   // softmax of zero logits
            } else {
                float lg = 0.0f;
                {
                    const float4* vp = reinterpret_cast<const float4*>(v0 + ((size_t)b * N_NCAPS + j) * N_DIMS + d0);
                    float4 va = vp[0], vb = vp[1];
                    float vr[8] = {va.x, va.y, va.z, va.w, vb.x, vb.y, vb.z, vb.w};
                    #pragma unroll
                    for (int dd = 0; dd < 8; ++dd) lg = fmaf(u[dd], vr[dd], lg);
                }
                if (T == 2) {
                    const float4* vp = reinterpret_cast<const float4*>(v1 + ((size_t)b * N_NCAPS + j) * N_DIMS + d0);
                    float4 va = vp[0], vb = vp[1];
                    float vr[8] = {va.x, va.y, va.z, va.w, vb.x, vb.y, vb.z, vb.w};
                    #pragma unroll
                    for (int dd = 0; dd < 8; ++dd) lg = fmaf(u[dd], vr[dd], lg);
                }
                lg += __shfl_xor(lg, 1);   // full 16-d dot; both halves of j get it
                // softmax over 32 j's: masks 2..32 keep the two duplicate
                // halves separate -> each lane's reduction spans all 32 j exactly once
                float m = lg;
                #pragma unroll
                for (int mask = 2; mask < 64; mask <<= 1) m = fmaxf(m, __shfl_xor(m, mask));
                float e = __expf(lg - m);
                float ssum = e;
                #pragma unroll
                for (int mask = 2; mask < 64; mask <<= 1) ssum += __shfl_xor(ssum, mask);
                c = e / ssum;
                if (T == 2 && d0 == 0)
                    c_out[((size_t)b * N_ICAPS + i) * N_NCAPS + j] = c;
            }
            #pragma unroll
            for (int dd = 0; dd < 8; ++dd) sacc[bb][dd] = fmaf(c, u[dd], sacc[bb][dd]);
        }
    }

    // block-level reduction: 8 waves share the same b-octet
    for (int idx = tid; idx < 4096; idx += 512) s_lds[idx] = 0.0f;
    __syncthreads();
    #pragma unroll
    for (int bb = 0; bb < 8; ++bb)
        #pragma unroll
        for (int dd = 0; dd < 8; ++dd) {
            // c is already folded into sacc (including the 1/32 for T==0)
            atomicAdd(&s_lds[bb * 512 + l * 8 + dd], sacc[bb][dd]);
        }
    __syncthreads();
    for (int idx = tid; idx < 4096; idx += 512) {
        int bb = idx >> 9, jd = idx & 511;
        s_part[((size_t)ci * 64 + b0 + bb) * 512 + jd] = s_lds[idx];
    }
}

// K3: sum partials over 64 i-chunks, squash, write v[b, j, d]
__global__ __launch_bounds__(512) void reduce_squash(const float* __restrict__ s_part,
                                                     float* __restrict__ v_out) {
    const int b = blockIdx.x;
    const int tid = threadIdx.x;   // j*16 + d
    float acc = 0.0f;
    #pragma unroll 8
    for (int ci = 0; ci < 64; ++ci) acc += s_part[((size_t)ci * 64 + b) * 512 + tid];
    float s2 = acc * acc;
    #pragma unroll
    for (int mask = 1; mask < 16; mask <<= 1) s2 += __shfl_xor(s2, mask);
    float vv = acc * (s2 / (1.0f + s2)) * (1.0f / sqrtf(s2 + 1e-7f));
    v_out[(size_t)b * 512 + tid] = vv;
}

extern "C" void kernel_launch(void* const* d_in, const int* in_sizes, int n_in,
                              void* d_out, int out_size, void* d_ws, size_t ws_size,
                              hipStream_t stream) {
    const float* x   = (const float*)d_in[0];
    const float* loc = (const float*)d_in[1];
    const float* sr  = (const float*)d_in[2];
    const float* eps = (const float*)d_in[3];
    float* out = (float*)d_out;

    float* W      = (float*)d_ws;            // 8,388,608 floats
    float* s_part = W + 8388608;             // 64*64*512 = 2,097,152 floats
    float* v0b    = s_part + 2097152;        // 32,768 floats
    float* v1b    = v0b + 32768;             // 32,768 floats
    float* c_out  = out + 32768;             // routing weights [64,2048,32]

    compute_w<<<8192, 256, 0, stream>>>((const float4*)loc, (const float4*)sr,
                                        (const float4*)eps, (float4*)W);
    route_pass<0><<<512, 512, 0, stream>>>(W, x, nullptr, nullptr, s_part, nullptr);
    reduce_squash<<<64, 512, 0, stream>>>(s_part, v0b);
    route_pass<1><<<512, 512, 0, stream>>>(W, x, v0b, nullptr, s_part, nullptr);
    reduce_squash<<<64, 512, 0, stream>>>(s_part, v1b);
    route_pass<2><<<512, 512, 0, stream>>>(W, x, v0b, v1b, s_part, c_out);
    reduce_squash<<<64, 512, 0, stream>>>(s_part, out);
}

// Round 5
// 707.789 us; speedup vs baseline: 1.0111x; 1.0111x over previous
//
#include <hip/hip_runtime.h>
#include <math.h>

#define N_B 64
#define N_ICAPS 2048
#define N_IDIMS 8
#define N_NCAPS 32
#define N_DIMS 16

__device__ __forceinline__ float softplus_f(float z) {
    return (z > 15.0f) ? z : log1pf(__expf(z));
}

// K1: W = loc + (1e-5 + softplus(C + scale_raw)) * eps    (8,388,608 floats)
__global__ __launch_bounds__(256) void compute_w(const float4* __restrict__ loc,
                                                 const float4* __restrict__ sr,
                                                 const float4* __restrict__ eps,
                                                 float4* __restrict__ W) {
    const float C = 0.5413248546129181f;  // log(expm1(1))
    int idx = blockIdx.x * 256 + threadIdx.x;   // 2,097,152 float4s total
    float4 l = loc[idx], s = sr[idx], e = eps[idx];
    float4 o;
    o.x = fmaf(1e-5f + softplus_f(C + s.x), e.x, l.x);
    o.y = fmaf(1e-5f + softplus_f(C + s.y), e.y, l.y);
    o.z = fmaf(1e-5f + softplus_f(C + s.z), e.z, l.z);
    o.w = fmaf(1e-5f + softplus_f(C + s.w), e.w, l.w);
    W[idx] = o;
}

// K2: one routing pass. T = iteration index (0,1,2).
// Grid: 512 blocks = 8 b-groups x 64 i-chunks; block = 8 waves (512 thr).
// Wave w handles b in [bg*8, bg*8+8), i in [ci*32 + w*4, +4).
// Lane l: j = l>>1, d-range = (l&1)*8 .. +8.
//
// Register budget: live set ~178 VGPR (Wr[64] + sacc[64] + temps).
// __launch_bounds__(512,2) and (512,1) both produced VGPR_Count=128 with
// ~134 MB/dispatch scratch spill (R3/R4 profiles: WRITE 142 MB vs 8 MB
// legit, VALUBusy 7.8%). Force the allocator instead via amdgpu attrs:
// waves_per_eu(2,2) -> 256-VGPR budget, same occupancy (a 512-thr block
// is exactly 2 waves/SIMD), zero spill.
template<int T>
__global__
__attribute__((amdgpu_flat_work_group_size(512, 512)))
__attribute__((amdgpu_waves_per_eu(2, 2)))
void route_pass(
        const float* __restrict__ W, const float* __restrict__ x,
        const float* __restrict__ v0, const float* __restrict__ v1,
        float* __restrict__ s_part, float* __restrict__ c_out) {
    __shared__ float s_lds[8 * 512];
    const int tid = threadIdx.x;
    const int w = tid >> 6;
    const int l = tid & 63;
    const int bg = blockIdx.x & 7;
    const int ci = blockIdx.x >> 3;
    const int b0 = bg * 8;
    const int i0 = ci * 32 + w * 4;
    const int j = l >> 1;
    const int d0 = (l & 1) * 8;

    float sacc[8][8];
    #pragma unroll
    for (int a = 0; a < 8; ++a)
        #pragma unroll
        for (int c2 = 0; c2 < 8; ++c2) sacc[a][c2] = 0.0f;

    for (int ii = 0; ii < 4; ++ii) {
        const int i = i0 + ii;
        // lane's W slice: 64 consecutive floats at W + i*4096 + l*64
        // = W[i][j = l>>1][d0 + 0..7][0..7]  (row-major i,j,d,k)
        float Wr[64];
        const float4* wp = reinterpret_cast<const float4*>(W + (size_t)i * 4096 + l * 64);
        #pragma unroll
        for (int q = 0; q < 16; ++q) {
            float4 t = wp[q];
            Wr[q * 4 + 0] = t.x; Wr[q * 4 + 1] = t.y;
            Wr[q * 4 + 2] = t.z; Wr[q * 4 + 3] = t.w;
        }
        #pragma unroll
        for (int bb = 0; bb < 8; ++bb) {
            const int b = b0 + bb;
            const float4* xp = reinterpret_cast<const float4*>(x + ((size_t)b * N_ICAPS + i) * N_IDIMS);
            float4 xa = xp[0], xb = xp[1];
            float xr[8] = {xa.x, xa.y, xa.z, xa.w, xb.x, xb.y, xb.z, xb.w};
            float u[8];
            #pragma unroll
            for (int dd = 0; dd < 8; ++dd) {
                float acc = 0.0f;
                #pragma unroll
                for (int k = 0; k < 8; ++k) acc = fmaf(Wr[dd * 8 + k], xr[k], acc);
                u[dd] = acc;
            }
            float c;
            if (T == 0) {
                c = 1.0f / 32.0f;   // softmax of zero logits
            } else {
                float lg = 0.0f;
                {
                    const float4* vp = reinterpret_cast<const float4*>(v0 + ((size_t)b * N_NCAPS + j) * N_DIMS + d0);
                    float4 va = vp[0], vb = vp[1];
                    float vr[8] = {va.x, va.y, va.z, va.w, vb.x, vb.y, vb.z, vb.w};
                    #pragma unroll
                    for (int dd = 0; dd < 8; ++dd) lg = fmaf(u[dd], vr[dd], lg);
                }
                if (T == 2) {
                    const float4* vp = reinterpret_cast<const float4*>(v1 + ((size_t)b * N_NCAPS + j) * N_DIMS + d0);
                    float4 va = vp[0], vb = vp[1];
                    float vr[8] = {va.x, va.y, va.z, va.w, vb.x, vb.y, vb.z, vb.w};
                    #pragma unroll
                    for (int dd = 0; dd < 8; ++dd) lg = fmaf(u[dd], vr[dd], lg);
                }
                lg += __shfl_xor(lg, 1);   // full 16-d dot; both halves of j get it
                // softmax over 32 j's: masks 2..32 keep the two duplicate
                // halves separate -> each lane's reduction spans all 32 j exactly once
                float m = lg;
                #pragma unroll
                for (int mask = 2; mask < 64; mask <<= 1) m = fmaxf(m, __shfl_xor(m, mask));
                float e = __expf(lg - m);
                float ssum = e;
                #pragma unroll
                for (int mask = 2; mask < 64; mask <<= 1) ssum += __shfl_xor(ssum, mask);
                c = e / ssum;
                if (T == 2 && d0 == 0)
                    c_out[((size_t)b * N_ICAPS + i) * N_NCAPS + j] = c;
            }
            #pragma unroll
            for (int dd = 0; dd < 8; ++dd) sacc[bb][dd] = fmaf(c, u[dd], sacc[bb][dd]);
        }
    }

    // block-level reduction: 8 waves share the same b-octet
    for (int idx = tid; idx < 4096; idx += 512) s_lds[idx] = 0.0f;
    __syncthreads();
    #pragma unroll
    for (int bb = 0; bb < 8; ++bb)
        #pragma unroll
        for (int dd = 0; dd < 8; ++dd) {
            // c is already folded into sacc (including the 1/32 for T==0)
            atomicAdd(&s_lds[bb * 512 + l * 8 + dd], sacc[bb][dd]);
        }
    __syncthreads();
    for (int idx = tid; idx < 4096; idx += 512) {
        int bb = idx >> 9, jd = idx & 511;
        s_part[((size_t)ci * 64 + b0 + bb) * 512 + jd] = s_lds[idx];
    }
}

// K3: sum partials over 64 i-chunks, squash, write v[b, j, d]
__global__ __launch_bounds__(512) void reduce_squash(const float* __restrict__ s_part,
                                                     float* __restrict__ v_out) {
    const int b = blockIdx.x;
    const int tid = threadIdx.x;   // j*16 + d
    float acc = 0.0f;
    #pragma unroll 8
    for (int ci = 0; ci < 64; ++ci) acc += s_part[((size_t)ci * 64 + b) * 512 + tid];
    float s2 = acc * acc;
    #pragma unroll
    for (int mask = 1; mask < 16; mask <<= 1) s2 += __shfl_xor(s2, mask);
    float vv = acc * (s2 / (1.0f + s2)) * (1.0f / sqrtf(s2 + 1e-7f));
    v_out[(size_t)b * 512 + tid] = vv;
}

extern "C" void kernel_launch(void* const* d_in, const int* in_sizes, int n_in,
                              void* d_out, int out_size, void* d_ws, size_t ws_size,
                              hipStream_t stream) {
    const float* x   = (const float*)d_in[0];
    const float* loc = (const float*)d_in[1];
    const float* sr  = (const float*)d_in[2];
    const float* eps = (const float*)d_in[3];
    float* out = (float*)d_out;

    float* W      = (float*)d_ws;            // 8,388,608 floats
    float* s_part = W + 8388608;             // 64*64*512 = 2,097,152 floats
    float* v0b    = s_part + 2097152;        // 32,768 floats
    float* v1b    = v0b + 32768;             // 32,768 floats
    float* c_out  = out + 32768;             // routing weights [64,2048,32]

    compute_w<<<8192, 256, 0, stream>>>((const float4*)loc, (const float4*)sr,
                                        (const float4*)eps, (float4*)W);
    route_pass<0><<<512, 512, 0, stream>>>(W, x, nullptr, nullptr, s_part, nullptr);
    reduce_squash<<<64, 512, 0, stream>>>(s_part, v0b);
    route_pass<1><<<512, 512, 0, stream>>>(W, x, v0b, nullptr, s_part, nullptr);
    reduce_squash<<<64, 512, 0, stream>>>(s_part, v1b);
    route_pass<2><<<512, 512, 0, stream>>>(W, x, v0b, v1b, s_part, c_out);
    reduce_squash<<<64, 512, 0, stream>>>(s_part, out);
}

// Round 6
// 653.687 us; speedup vs baseline: 1.0948x; 1.0828x over previous
//
#include <hip/hip_runtime.h>
#include <math.h>

#define N_B 64
#define N_ICAPS 2048
#define N_IDIMS 8
#define N_NCAPS 32
#define N_DIMS 16

__device__ __forceinline__ float softplus_f(float z) {
    return (z > 15.0f) ? z : log1pf(__expf(z));
}

// K1: W = loc + (1e-5 + softplus(C + scale_raw)) * eps    (8,388,608 floats)
__global__ __launch_bounds__(256) void compute_w(const float4* __restrict__ loc,
                                                 const float4* __restrict__ sr,
                                                 const float4* __restrict__ eps,
                                                 float4* __restrict__ W) {
    const float C = 0.5413248546129181f;  // log(expm1(1))
    int idx = blockIdx.x * 256 + threadIdx.x;   // 2,097,152 float4s total
    float4 l = loc[idx], s = sr[idx], e = eps[idx];
    float4 o;
    o.x = fmaf(1e-5f + softplus_f(C + s.x), e.x, l.x);
    o.y = fmaf(1e-5f + softplus_f(C + s.y), e.y, l.y);
    o.z = fmaf(1e-5f + softplus_f(C + s.z), e.z, l.z);
    o.w = fmaf(1e-5f + softplus_f(C + s.w), e.w, l.w);
    W[idx] = o;
}

// K2: one routing pass. T = iteration index (0,1,2).
// Grid: 1024 blocks = 16 b-groups x 64 i-chunks; block = 8 waves (512 thr).
// b-tile = 4 (sacc[4][8]=32 regs): peak live ~125 VGPR fits the 128 the
// allocator insists on (R3/R4/R5: 8-b tile -> 178 live -> ~140 MB/dispatch
// scratch spill, VALUBusy 7.8%).
// XCD swizzle: hardware round-robins blockIdx over 8 XCDs (xcd = B % 8).
// Decode so all 16 bg for a given ci land on one XCD -> W slice set per
// XCD = 8 x 524 KB ~ 4.2 MB ~ its private L2 -> W HBM fetch ~1x not ~8x.
// Wave w handles i in [ci*32 + w*4, +4); lane l: j = l>>1, d0 = (l&1)*8.
template<int T>
__global__ __launch_bounds__(512, 2) void route_pass(
        const float* __restrict__ W, const float* __restrict__ x,
        const float* __restrict__ v0, const float* __restrict__ v1,
        float* __restrict__ s_part, float* __restrict__ c_out) {
    __shared__ float s_lds[4 * 512];
    const int tid = threadIdx.x;
    const int w = tid >> 6;
    const int l = tid & 63;
    const int B = blockIdx.x;
    const int xcd = B & 7;          // hw XCD (round-robin dispatch)
    const int q = B >> 3;           // 0..127
    const int ci = xcd * 8 + (q & 7);   // 64 i-chunks, 8 per XCD
    const int bg = q >> 3;          // 0..15
    const int b0 = bg * 4;
    const int i0 = ci * 32 + w * 4;
    const int j = l >> 1;
    const int d0 = (l & 1) * 8;

    float sacc[4][8];
    #pragma unroll
    for (int a = 0; a < 4; ++a)
        #pragma unroll
        for (int c2 = 0; c2 < 8; ++c2) sacc[a][c2] = 0.0f;

    for (int ii = 0; ii < 4; ++ii) {
        const int i = i0 + ii;
        // lane's W slice: 64 consecutive floats at W + i*4096 + l*64
        // = W[i][j = l>>1][d0 + 0..7][0..7]  (row-major i,j,d,k)
        float Wr[64];
        const float4* wp = reinterpret_cast<const float4*>(W + (size_t)i * 4096 + l * 64);
        #pragma unroll
        for (int qq = 0; qq < 16; ++qq) {
            float4 t = wp[qq];
            Wr[qq * 4 + 0] = t.x; Wr[qq * 4 + 1] = t.y;
            Wr[qq * 4 + 2] = t.z; Wr[qq * 4 + 3] = t.w;
        }
        #pragma unroll
        for (int bb = 0; bb < 4; ++bb) {
            const int b = b0 + bb;
            const float4* xp = reinterpret_cast<const float4*>(x + ((size_t)b * N_ICAPS + i) * N_IDIMS);
            float4 xa = xp[0], xb = xp[1];
            float xr[8] = {xa.x, xa.y, xa.z, xa.w, xb.x, xb.y, xb.z, xb.w};
            float u[8];
            #pragma unroll
            for (int dd = 0; dd < 8; ++dd) {
                float acc = 0.0f;
                #pragma unroll
                for (int k = 0; k < 8; ++k) acc = fmaf(Wr[dd * 8 + k], xr[k], acc);
                u[dd] = acc;
            }
            float c;
            if (T == 0) {
                c = 1.0f / 32.0f;   // softmax of zero logits
            } else {
                float lg = 0.0f;
                {
                    const float4* vp = reinterpret_cast<const float4*>(v0 + ((size_t)b * N_NCAPS + j) * N_DIMS + d0);
                    float4 va = vp[0], vb = vp[1];
                    float vr[8] = {va.x, va.y, va.z, va.w, vb.x, vb.y, vb.z, vb.w};
                    #pragma unroll
                    for (int dd = 0; dd < 8; ++dd) lg = fmaf(u[dd], vr[dd], lg);
                }
                if (T == 2) {
                    const float4* vp = reinterpret_cast<const float4*>(v1 + ((size_t)b * N_NCAPS + j) * N_DIMS + d0);
                    float4 va = vp[0], vb = vp[1];
                    float vr[8] = {va.x, va.y, va.z, va.w, vb.x, vb.y, vb.z, vb.w};
                    #pragma unroll
                    for (int dd = 0; dd < 8; ++dd) lg = fmaf(u[dd], vr[dd], lg);
                }
                lg += __shfl_xor(lg, 1);   // full 16-d dot; both halves of j get it
                // softmax over 32 j's: masks 2..32 keep the two duplicate
                // halves separate -> each lane's reduction spans all 32 j exactly once
                float m = lg;
                #pragma unroll
                for (int mask = 2; mask < 64; mask <<= 1) m = fmaxf(m, __shfl_xor(m, mask));
                float e = __expf(lg - m);
                float ssum = e;
                #pragma unroll
                for (int mask = 2; mask < 64; mask <<= 1) ssum += __shfl_xor(ssum, mask);
                c = e / ssum;
                if (T == 2 && d0 == 0)
                    c_out[((size_t)b * N_ICAPS + i) * N_NCAPS + j] = c;
            }
            #pragma unroll
            for (int dd = 0; dd < 8; ++dd) sacc[bb][dd] = fmaf(c, u[dd], sacc[bb][dd]);
        }
    }

    // block-level reduction: 8 waves share the same b-quad
    for (int idx = tid; idx < 2048; idx += 512) s_lds[idx] = 0.0f;
    __syncthreads();
    #pragma unroll
    for (int bb = 0; bb < 4; ++bb)
        #pragma unroll
        for (int dd = 0; dd < 8; ++dd) {
            // c is already folded into sacc (including the 1/32 for T==0)
            atomicAdd(&s_lds[bb * 512 + l * 8 + dd], sacc[bb][dd]);
        }
    __syncthreads();
    for (int idx = tid; idx < 2048; idx += 512) {
        int bb = idx >> 9, jd = idx & 511;
        s_part[((size_t)ci * 64 + b0 + bb) * 512 + jd] = s_lds[idx];
    }
}

// K3: sum partials over 64 i-chunks, squash, write v[b, j, d]
__global__ __launch_bounds__(512) void reduce_squash(const float* __restrict__ s_part,
                                                     float* __restrict__ v_out) {
    const int b = blockIdx.x;
    const int tid = threadIdx.x;   // j*16 + d
    float acc = 0.0f;
    #pragma unroll 8
    for (int ci = 0; ci < 64; ++ci) acc += s_part[((size_t)ci * 64 + b) * 512 + tid];
    float s2 = acc * acc;
    #pragma unroll
    for (int mask = 1; mask < 16; mask <<= 1) s2 += __shfl_xor(s2, mask);
    float vv = acc * (s2 / (1.0f + s2)) * (1.0f / sqrtf(s2 + 1e-7f));
    v_out[(size_t)b * 512 + tid] = vv;
}

extern "C" void kernel_launch(void* const* d_in, const int* in_sizes, int n_in,
                              void* d_out, int out_size, void* d_ws, size_t ws_size,
                              hipStream_t stream) {
    const float* x   = (const float*)d_in[0];
    const float* loc = (const float*)d_in[1];
    const float* sr  = (const float*)d_in[2];
    const float* eps = (const float*)d_in[3];
    float* out = (float*)d_out;

    float* W      = (float*)d_ws;            // 8,388,608 floats
    float* s_part = W + 8388608;             // 64*64*512 = 2,097,152 floats
    float* v0b    = s_part + 2097152;        // 32,768 floats
    float* v1b    = v0b + 32768;             // 32,768 floats
    float* c_out  = out + 32768;             // routing weights [64,2048,32]

    compute_w<<<8192, 256, 0, stream>>>((const float4*)loc, (const float4*)sr,
                                        (const float4*)eps, (float4*)W);
    route_pass<0><<<1024, 512, 0, stream>>>(W, x, nullptr, nullptr, s_part, nullptr);
    reduce_squash<<<64, 512, 0, stream>>>(s_part, v0b);
    route_pass<1><<<1024, 512, 0, stream>>>(W, x, v0b, nullptr, s_part, nullptr);
    reduce_squash<<<64, 512, 0, stream>>>(s_part, v1b);
    route_pass<2><<<1024, 512, 0, stream>>>(W, x, v0b, v1b, s_part, c_out);
    reduce_squash<<<64, 512, 0, stream>>>(s_part, out);
}

// Round 11
// 524.742 us; speedup vs baseline: 1.3638x; 1.2457x over previous
//
#include <hip/hip_runtime.h>
#include <math.h>

#define N_B 64
#define N_ICAPS 2048
#define N_IDIMS 8
#define N_NCAPS 32
#define N_DIMS 16

__device__ __forceinline__ float softplus_f(float z) {
    return (z > 15.0f) ? z : log1pf(__expf(z));
}

// K1: W = loc + (1e-5 + softplus(C + scale_raw)) * eps, scattered into a
// wave-friendly layout W2:
//   float4 index = i*1024 + qq*64 + l,  l = j*2 + (d>=8), qq = (d&7)*2 + khalf
// so that route_pass lane l reads its 64-float fragment as wp[qq*64 + l]:
// 64 lanes x consecutive float4 = 1 KB contiguous per load instruction.
// (R6 evidence: old layout had lane-stride 256 B -> 64 cache lines per
// load instr; even shuffle-free route_pass<0> sat at 200 us, VALUBusy 10%.)
__global__ __launch_bounds__(256) void compute_w(const float4* __restrict__ loc,
                                                 const float4* __restrict__ sr,
                                                 const float4* __restrict__ eps,
                                                 float4* __restrict__ W2) {
    const float C = 0.5413248546129181f;  // log(expm1(1))
    int f = blockIdx.x * 256 + threadIdx.x;   // 2,097,152 float4s total
    float4 l = loc[f], s = sr[f], e = eps[f];
    float4 o;
    o.x = fmaf(1e-5f + softplus_f(C + s.x), e.x, l.x);
    o.y = fmaf(1e-5f + softplus_f(C + s.y), e.y, l.y);
    o.z = fmaf(1e-5f + softplus_f(C + s.z), e.z, l.z);
    o.w = fmaf(1e-5f + softplus_f(C + s.w), e.w, l.w);
    // flat float4 f = (((i*32 + j)*16 + d)*8 + k)/4
    int i    = f >> 10;
    int j    = (f >> 5) & 31;
    int d    = (f >> 1) & 15;
    int kh   = f & 1;
    int lcol = j * 2 + (d >> 3);
    int qq   = (d & 7) * 2 + kh;
    W2[((size_t)i << 10) + qq * 64 + lcol] = o;
}

// K2: one routing pass. T = iteration index (0,1,2).
// Grid: 1024 blocks = 16 b-groups x 64 i-chunks; block = 8 waves (512 thr).
// XCD swizzle: all 16 bg for a ci-octet land on one XCD -> W slices L2-hot.
// Wave w: i in [ci*32 + w*4, +4). Lane l: j = l>>1, d0 = (l&1)*8.
// b-tile = 4 (sacc[4][8]); softmax: no max-subtract (|logit| <~ 6, softmax
// is shift-invariant), sum-butterfly batched 4-wide across bb for ILP on
// the cross-lane chain; u recomputed after softmax instead of held
// (VALU 10% busy -> FMAs free, VGPRs not).
template<int T>
__global__ __launch_bounds__(512, 2) void route_pass(
        const float* __restrict__ W, const float* __restrict__ x,
        const float* __restrict__ v0, const float* __restrict__ v1,
        float* __restrict__ s_part, float* __restrict__ c_out) {
    __shared__ float s_lds[4 * 512];
    const int tid = threadIdx.x;
    const int w = tid >> 6;
    const int l = tid & 63;
    const int B = blockIdx.x;
    const int xcd = B & 7;          // hw XCD (round-robin dispatch)
    const int q = B >> 3;           // 0..127
    const int ci = xcd * 8 + (q & 7);   // 64 i-chunks, 8 per XCD
    const int bg = q >> 3;          // 0..15
    const int b0 = bg * 4;
    const int i0 = ci * 32 + w * 4;
    const int j = l >> 1;
    const int d0 = (l & 1) * 8;

    float sacc[4][8];
    #pragma unroll
    for (int a = 0; a < 4; ++a)
        #pragma unroll
        for (int c2 = 0; c2 < 8; ++c2) sacc[a][c2] = 0.0f;

    for (int ii = 0; ii < 4; ++ii) {
        const int i = i0 + ii;
        // lane fragment: Wr[qq*4+c] = W[i, j, d0 + (qq>>1), k]  (coalesced)
        float Wr[64];
        const float4* wp = reinterpret_cast<const float4*>(W) + ((size_t)i << 10) + l;
        #pragma unroll
        for (int qq = 0; qq < 16; ++qq) {
            float4 t = wp[qq * 64];
            Wr[qq * 4 + 0] = t.x; Wr[qq * 4 + 1] = t.y;
            Wr[qq * 4 + 2] = t.z; Wr[qq * 4 + 3] = t.w;
        }

        if (T == 0) {
            #pragma unroll
            for (int bb = 0; bb < 4; ++bb) {
                const int b = b0 + bb;
                const float4* xp = reinterpret_cast<const float4*>(x + ((size_t)b * N_ICAPS + i) * N_IDIMS);
                float4 xa = xp[0], xb = xp[1];
                float xr[8] = {xa.x, xa.y, xa.z, xa.w, xb.x, xb.y, xb.z, xb.w};
                #pragma unroll
                for (int dd = 0; dd < 8; ++dd) {
                    float acc = 0.0f;
                    #pragma unroll
                    for (int k = 0; k < 8; ++k) acc = fmaf(Wr[dd * 8 + k], xr[k], acc);
                    sacc[bb][dd] = fmaf(0.03125f, acc, sacc[bb][dd]);
                }
            }
        } else {
            // phase 1: half-dot logits for 4 b's
            float lgh[4];
            #pragma unroll
            for (int bb = 0; bb < 4; ++bb) {
                const int b = b0 + bb;
                const float4* xp = reinterpret_cast<const float4*>(x + ((size_t)b * N_ICAPS + i) * N_IDIMS);
                float4 xa = xp[0], xb = xp[1];
                float xr[8] = {xa.x, xa.y, xa.z, xa.w, xb.x, xb.y, xb.z, xb.w};
                float u[8];
                #pragma unroll
                for (int dd = 0; dd < 8; ++dd) {
                    float acc = 0.0f;
                    #pragma unroll
                    for (int k = 0; k < 8; ++k) acc = fmaf(Wr[dd * 8 + k], xr[k], acc);
                    u[dd] = acc;
                }
                float lg = 0.0f;
                {
                    const float4* vp = reinterpret_cast<const float4*>(v0 + ((size_t)b * N_NCAPS + j) * N_DIMS + d0);
                    float4 va = vp[0], vb = vp[1];
                    float vr[8] = {va.x, va.y, va.z, va.w, vb.x, vb.y, vb.z, vb.w};
                    #pragma unroll
                    for (int dd = 0; dd < 8; ++dd) lg = fmaf(u[dd], vr[dd], lg);
                }
                if (T == 2) {
                    const float4* vp = reinterpret_cast<const float4*>(v1 + ((size_t)b * N_NCAPS + j) * N_DIMS + d0);
                    float4 va = vp[0], vb = vp[1];
                    float vr[8] = {va.x, va.y, va.z, va.w, vb.x, vb.y, vb.z, vb.w};
                    #pragma unroll
                    for (int dd = 0; dd < 8; ++dd) lg = fmaf(u[dd], vr[dd], lg);
                }
                lgh[bb] = lg;
            }
            // phase 2: batched softmax (4-wide ILP on the cross-lane chain)
            float ef[4], ss[4], cr[4];
            #pragma unroll
            for (int bb = 0; bb < 4; ++bb) lgh[bb] += __shfl_xor(lgh[bb], 1);
            #pragma unroll
            for (int bb = 0; bb < 4; ++bb) ef[bb] = __expf(lgh[bb]);
            #pragma unroll
            for (int bb = 0; bb < 4; ++bb) ss[bb] = ef[bb];
            #pragma unroll
            for (int mask = 2; mask < 64; mask <<= 1)
                #pragma unroll
                for (int bb = 0; bb < 4; ++bb) ss[bb] += __shfl_xor(ss[bb], mask);
            #pragma unroll
            for (int bb = 0; bb < 4; ++bb)
                cr[bb] = ef[bb] / ss[bb];
            if (T == 2 && d0 == 0) {
                #pragma unroll
                for (int bb = 0; bb < 4; ++bb)
                    c_out[(((size_t)(b0 + bb)) * N_ICAPS + i) * N_NCAPS + j] = cr[bb];
            }
            // phase 3: recompute u, accumulate c*u
            #pragma unroll
            for (int bb = 0; bb < 4; ++bb) {
                const int b = b0 + bb;
                const float4* xp = reinterpret_cast<const float4*>(x + ((size_t)b * N_ICAPS + i) * N_IDIMS);
                float4 xa = xp[0], xb = xp[1];
                float xr[8] = {xa.x, xa.y, xa.z, xa.w, xb.x, xb.y, xb.z, xb.w};
                #pragma unroll
                for (int dd = 0; dd < 8; ++dd) {
                    float acc = 0.0f;
                    #pragma unroll
                    for (int k = 0; k < 8; ++k) acc = fmaf(Wr[dd * 8 + k], xr[k], acc);
                    sacc[bb][dd] = fmaf(cr[bb], acc, sacc[bb][dd]);
                }
            }
        }
    }

    // block-level reduction: 8 waves share the same b-quad
    for (int idx = tid; idx < 2048; idx += 512) s_lds[idx] = 0.0f;
    __syncthreads();
    #pragma unroll
    for (int bb = 0; bb < 4; ++bb)
        #pragma unroll
        for (int dd = 0; dd < 8; ++dd) {
            atomicAdd(&s_lds[bb * 512 + l * 8 + dd], sacc[bb][dd]);
        }
    __syncthreads();
    for (int idx = tid; idx < 2048; idx += 512) {
        int bb = idx >> 9, jd = idx & 511;
        s_part[((size_t)ci * 64 + b0 + bb) * 512 + jd] = s_lds[idx];
    }
}

// K3: sum partials over 64 i-chunks, squash, write v[b, j, d]
__global__ __launch_bounds__(512) void reduce_squash(const float* __restrict__ s_part,
                                                     float* __restrict__ v_out) {
    const int b = blockIdx.x;
    const int tid = threadIdx.x;   // j*16 + d
    float acc = 0.0f;
    #pragma unroll 8
    for (int ci = 0; ci < 64; ++ci) acc += s_part[((size_t)ci * 64 + b) * 512 + tid];
    float s2 = acc * acc;
    #pragma unroll
    for (int mask = 1; mask < 16; mask <<= 1) s2 += __shfl_xor(s2, mask);
    float vv = acc * (s2 / (1.0f + s2)) * (1.0f / sqrtf(s2 + 1e-7f));
    v_out[(size_t)b * 512 + tid] = vv;
}

extern "C" void kernel_launch(void* const* d_in, const int* in_sizes, int n_in,
                              void* d_out, int out_size, void* d_ws, size_t ws_size,
                              hipStream_t stream) {
    const float* x   = (const float*)d_in[0];
    const float* loc = (const float*)d_in[1];
    const float* sr  = (const float*)d_in[2];
    const float* eps = (const float*)d_in[3];
    float* out = (float*)d_out;

    float* W      = (float*)d_ws;            // 8,388,608 floats (permuted layout)
    float* s_part = W + 8388608;             // 64*64*512 = 2,097,152 floats
    float* v0b    = s_part + 2097152;        // 32,768 floats
    float* v1b    = v0b + 32768;             // 32,768 floats
    float* c_out  = out + 32768;             // routing weights [64,2048,32]

    compute_w<<<8192, 256, 0, stream>>>((const float4*)loc, (const float4*)sr,
                                        (const float4*)eps, (float4*)W);
    route_pass<0><<<1024, 512, 0, stream>>>(W, x, nullptr, nullptr, s_part, nullptr);
    reduce_squash<<<64, 512, 0, stream>>>(s_part, v0b);
    route_pass<1><<<1024, 512, 0, stream>>>(W, x, v0b, nullptr, s_part, nullptr);
    reduce_squash<<<64, 512, 0, stream>>>(s_part, v1b);
    route_pass<2><<<1024, 512, 0, stream>>>(W, x, v0b, v1b, s_part, c_out);
    reduce_squash<<<64, 512, 0, stream>>>(s_part, out);
}